// Round 14
// baseline (597.190 us; speedup 1.0000x reference)
//
#include <hip/hip_runtime.h>
#include <math.h>

constexpr int BATCH = 256;
constexpr unsigned int NB = 1024;   // grid size; 4 blocks/CU x 256 CUs

typedef short short8 __attribute__((ext_vector_type(8)));
typedef float f32x4 __attribute__((ext_vector_type(4)));

// ---------------------------------------------------------------------------
// bf16 helpers (RNE)
// ---------------------------------------------------------------------------
__device__ __forceinline__ unsigned short f2bf(float f) {
    unsigned int u = __float_as_uint(f);
    u += 0x7FFFu + ((u >> 16) & 1u);
    return (unsigned short)(u >> 16);
}
__device__ __forceinline__ float bf2f(unsigned short h) {
    return __uint_as_float(((unsigned int)h) << 16);
}

// ---------------------------------------------------------------------------
// Manual grid barrier (persistent kernel; all NB blocks co-resident).
// Writer side: __syncthreads + ACQ_REL RMW (release flushes XCD L2);
// reader side: ACQUIRE spin load (invalidates L1/L2) + __syncthreads.
// Bounded spin: a residency failure produces wrong results, not a hang.
// ---------------------------------------------------------------------------
__device__ __forceinline__ void gsync(unsigned int* cnt, unsigned int target)
{
    __syncthreads();
    if (threadIdx.x == 0) {
        __hip_atomic_fetch_add(cnt, 1u, __ATOMIC_ACQ_REL, __HIP_MEMORY_SCOPE_AGENT);
        unsigned int spins = 0;
        while (__hip_atomic_load(cnt, __ATOMIC_ACQUIRE, __HIP_MEMORY_SCOPE_AGENT) < target) {
            __builtin_amdgcn_s_sleep(2);
            if (++spins > 100000000u) break;   // failsafe: fail visibly, not hang
        }
    }
    __syncthreads();
}

// ---------------------------------------------------------------------------
// basis_eval: 8 cubic B-spline values + silu. out[0..7]=basis, out[8]=silu.
// ---------------------------------------------------------------------------
__device__ __forceinline__ void basis_eval(
    float x, const float* __restrict__ grid, int ii, float out[9])
{
    float g[6];
#pragma unroll
    for (int k = 0; k < 6; ++k) g[k] = grid[(size_t)ii * 6 + k];
    float h = (g[5] - g[0]) * 0.2f;

    float t[12];
    t[0] = g[0] - 3.f * h; t[1] = g[0] - 2.f * h; t[2] = g[0] - h;
#pragma unroll
    for (int k = 0; k < 6; ++k) t[3 + k] = g[k];
    t[9] = g[5] + h; t[10] = g[5] + 2.f * h; t[11] = g[5] + 3.f * h;

    float Bv[11];
#pragma unroll
    for (int j = 0; j < 11; ++j)
        Bv[j] = (x >= t[j] && x < t[j + 1]) ? 1.0f : 0.0f;

#pragma unroll
    for (int d = 1; d <= 3; ++d) {
#pragma unroll
        for (int j = 0; j + d < 11; ++j) {
            float left  = __fdividef(x - t[j],         t[j + d] - t[j]);
            float right = __fdividef(t[j + d + 1] - x, t[j + d + 1] - t[j + 1]);
            Bv[j] = left * Bv[j] + right * Bv[j + 1];
        }
    }

#pragma unroll
    for (int k = 0; k < 8; ++k) out[k] = Bv[k];
    out[8] = __fdividef(x, 1.0f + __expf(-x));
}

// store 12 floats (last 3 zero) as a 24B bf16 record at rec (8B aligned)
__device__ __forceinline__ void store_rec12(unsigned short* rec, const float v[12])
{
    unsigned int u[6];
#pragma unroll
    for (int j = 0; j < 6; ++j)
        u[j] = (unsigned int)f2bf(v[2 * j]) | ((unsigned int)f2bf(v[2 * j + 1]) << 16);
    uint2* p = (uint2*)rec;
    p[0] = make_uint2(u[0], u[1]);
    p[1] = make_uint2(u[2], u[3]);
    p[2] = make_uint2(u[4], u[5]);
}

// load a 24B record -> 9 floats
__device__ __forceinline__ void load_rec12(const unsigned short* rec, float f[9])
{
    const uint2* p = (const uint2*)rec;
    uint2 q0 = p[0], q1 = p[1], q2 = p[2];
    f[0] = bf2f((unsigned short)q0.x); f[1] = bf2f((unsigned short)(q0.x >> 16));
    f[2] = bf2f((unsigned short)q0.y); f[3] = bf2f((unsigned short)(q0.y >> 16));
    f[4] = bf2f((unsigned short)q1.x); f[5] = bf2f((unsigned short)(q1.x >> 16));
    f[6] = bf2f((unsigned short)q1.y); f[7] = bf2f((unsigned short)(q1.y >> 16));
    f[8] = bf2f((unsigned short)q2.x);
}

// ---------------------------------------------------------------------------
// merge: wc9 record s (= o*I+ii): [ssp*coef0..7, sb, 0,0,0] bf16
// ---------------------------------------------------------------------------
__device__ __forceinline__ void merge_body(
    const float* __restrict__ coef, const float* __restrict__ ssp,
    const float* __restrict__ sb, unsigned short* __restrict__ wc9, int s)
{
    float sspv = ssp[s], sbv = sb[s];
    const float4* c = (const float4*)(coef + (size_t)s * 8);
    float4 c0 = c[0], c1 = c[1];
    float v[12] = { sspv * c0.x, sspv * c0.y, sspv * c0.z, sspv * c0.w,
                    sspv * c1.x, sspv * c1.y, sspv * c1.z, sspv * c1.w,
                    sbv, 0.f, 0.f, 0.f };
    store_rec12(wc9 + (size_t)s * 12, v);
}

// ---------------------------------------------------------------------------
// gemm0 fused (512 tasks = 32 mt x 16 nt): one 16x16 tile (m=ii, n=b),
// 4 waves split K (K2=3072 -> 24-MFMA chain each), LDS reduce.
// Epilogue: xmid = D + bias0 -> basis_eval -> bas9_1 records.
// ---------------------------------------------------------------------------
__device__ __forceinline__ void gemm0_fused(
    const unsigned short* __restrict__ wc9_0, const unsigned short* __restrict__ bas9_0,
    const float* __restrict__ bias0, const float* __restrict__ grid1,
    unsigned short* __restrict__ bas9_1, int bid, float (*T)[16][17])
{
    constexpr int K2 = 3072, KW = K2 / 4;
    int mt = bid >> 4, nt = bid & 15;
    int t = threadIdx.x, l = t & 63, w = t >> 6;
    int m0 = mt * 16;            // ii base (layer-1 input)
    int n0 = nt * 16;            // b base

    const unsigned short* pa = wc9_0  + (size_t)(m0 + (l & 15)) * K2 + w * KW + ((l >> 4) * 8);
    const unsigned short* pb = bas9_0 + (size_t)(n0 + (l & 15)) * K2 + w * KW + ((l >> 4) * 8);

    f32x4 acc = {0.f, 0.f, 0.f, 0.f};
#pragma unroll 8
    for (int kk = 0; kk < KW / 32; ++kk) {   // 24 steps
        short8 av = *(const short8*)pa; pa += 32;
        short8 bv = *(const short8*)pb; pb += 32;
        acc = __builtin_amdgcn_mfma_f32_16x16x32_bf16(av, bv, acc, 0, 0, 0);
    }

#pragma unroll
    for (int r = 0; r < 4; ++r)
        T[w][(l >> 4) * 4 + r][l & 15] = acc[r];   // [m_loc][n_loc]
    __syncthreads();

    int ii_loc = t & 15, b_loc = t >> 4;     // thread owns one element
    float d = T[0][ii_loc][b_loc] + T[1][ii_loc][b_loc]
            + T[2][ii_loc][b_loc] + T[3][ii_loc][b_loc];
    int ii = m0 + ii_loc;
    float xv = d + bias0[ii];
    float out[12];
    basis_eval(xv, grid1, ii, out);
    out[9] = 0.f; out[10] = 0.f; out[11] = 0.f;
    store_rec12(bas9_1 + ((size_t)(n0 + b_loc) * 512 + ii) * 12, out);
    __syncthreads();
}

// ---------------------------------------------------------------------------
// gemm1 fused (256 tasks = 16 mt x 16 nt): one 16x16 tile (m=b, n=o),
// 4 waves split K (K2=6144 -> 48-MFMA chain each), LDS reduce.
// Epilogue: x2[b][o] = D + bias1[o].
// ---------------------------------------------------------------------------
__device__ __forceinline__ void gemm1_fused(
    const unsigned short* __restrict__ bas9_1, const unsigned short* __restrict__ wc9_1,
    const float* __restrict__ bias1, float* __restrict__ x2, int bid, float (*T)[16][17])
{
    constexpr int K2 = 6144, KW = K2 / 4;
    int mt = bid >> 4, nt = bid & 15;
    int t = threadIdx.x, l = t & 63, w = t >> 6;
    int m0 = mt * 16;            // b base
    int n0 = nt * 16;            // o base

    const unsigned short* pa = bas9_1 + (size_t)(m0 + (l & 15)) * K2 + w * KW + ((l >> 4) * 8);
    const unsigned short* pb = wc9_1  + (size_t)(n0 + (l & 15)) * K2 + w * KW + ((l >> 4) * 8);

    f32x4 acc = {0.f, 0.f, 0.f, 0.f};
#pragma unroll 8
    for (int kk = 0; kk < KW / 32; ++kk) {   // 48 steps
        short8 av = *(const short8*)pa; pa += 32;
        short8 bv = *(const short8*)pb; pb += 32;
        acc = __builtin_amdgcn_mfma_f32_16x16x32_bf16(av, bv, acc, 0, 0, 0);
    }

#pragma unroll
    for (int r = 0; r < 4; ++r)
        T[w][(l >> 4) * 4 + r][l & 15] = acc[r];   // [b_loc][o_loc]
    __syncthreads();

    int o_loc = t & 15, b_loc = t >> 4;
    float d = T[0][b_loc][o_loc] + T[1][b_loc][o_loc]
            + T[2][b_loc][o_loc] + T[3][b_loc][o_loc];
    int o = n0 + o_loc;
    x2[(size_t)(m0 + b_loc) * 256 + o] = d + bias1[o];
}

// ---------------------------------------------------------------------------
// stats sweep: thread = ii (ii = isp*256+t), 8 o's in regs, BCH=32 b's/block.
// Reads bf16 records (24B each). spart: [8][3][O*I]
// ---------------------------------------------------------------------------
template <int I, int O>
__device__ __forceinline__ void stats_body(
    const unsigned short* __restrict__ bas9, const unsigned short* __restrict__ wc9,
    float* __restrict__ spart, int og, int ch, int isp)
{
    constexpr int OTB = 8, BCH = 32;
    const size_t OI = (size_t)O * I;
    int ii = isp * 256 + threadIdx.x;

    float wcr[OTB][9];
#pragma unroll
    for (int o = 0; o < OTB; ++o)
        load_rec12(wc9 + ((size_t)(og * OTB + o) * I + ii) * 12, wcr[o]);

    float aab[OTB], asum[OTB], asq[OTB];
#pragma unroll
    for (int o = 0; o < OTB; ++o) { aab[o] = 0.f; asum[o] = 0.f; asq[o] = 0.f; }

    for (int bl = 0; bl < BCH; ++bl) {
        int b = ch * BCH + bl;
        float f[9];
        load_rec12(bas9 + ((size_t)b * I + ii) * 12, f);
#pragma unroll
        for (int o = 0; o < OTB; ++o) {
            float y = wcr[o][8] * f[8];
#pragma unroll
            for (int p = 0; p < 8; ++p) y = fmaf(f[p], wcr[o][p], y);
            aab[o] += fabsf(y);
            asum[o] += y;
            asq[o] = fmaf(y, y, asq[o]);
        }
    }

    size_t cb = (size_t)ch * 3 * OI;
#pragma unroll
    for (int o = 0; o < OTB; ++o) {
        size_t s = (size_t)(og * OTB + o) * I + ii;
        spart[cb + s]          = aab[o];
        spart[cb + OI + s]     = asum[o];
        spart[cb + 2 * OI + s] = asq[o];
    }
}

__device__ __forceinline__ void statsfin_body(
    const float* __restrict__ spart, const float* __restrict__ grid,
    float* __restrict__ sc, float* __restrict__ st, int size, int s)
{
    float ab = 0.f, sm = 0.f, sq = 0.f;
#pragma unroll
    for (int k = 0; k < 8; ++k) {
        size_t base = (size_t)k * 3 * (size_t)size;
        ab += spart[base + s];
        sm += spart[base + (size_t)size + s];
        sq += spart[base + 2 * (size_t)size + s];
    }
    float range = grid[(size_t)s * 6 + 5] - grid[(size_t)s * 6 + 0] + 1e-4f;
    sc[s] = (ab * (1.0f / BATCH)) / range;
    float var = (sq - sm * sm * (1.0f / BATCH)) * (1.0f / (BATCH - 1));
    st[s] = sqrtf(fmaxf(var, 0.0f));
}

// ---------------------------------------------------------------------------
// Monolithic persistent kernel: 1024 blocks x 256 threads, 4 phases,
// manual grid barriers.
//   P1: basis0 (0-255) | merges (256-1023 covering 1024 tasks)
//   P2: gemm0-fused (0-511) | stats0 (512-1023)
//   P3: gemm1-fused (0-255) | stats1 (256-767) | statsfin0 half (768-1023)
//   P4: statsfin0 rest (0-255) | statsfin1 (0-511)
// ---------------------------------------------------------------------------
__global__ __launch_bounds__(256, 4) void kan_mono(
    const float* __restrict__ coef0, const float* __restrict__ ssp0,
    const float* __restrict__ sb0,   unsigned short* __restrict__ wc9_0,
    const float* __restrict__ coef1, const float* __restrict__ ssp1,
    const float* __restrict__ sb1,   unsigned short* __restrict__ wc9_1,
    const float* __restrict__ x,     const float* __restrict__ grid0,
    unsigned short* __restrict__ bas9_0,
    const float* __restrict__ bias0, const float* __restrict__ grid1,
    unsigned short* __restrict__ bas9_1,
    float* __restrict__ spart0, float* __restrict__ spart1,
    const float* __restrict__ bias1, float* __restrict__ x2,
    float* __restrict__ sc0, float* __restrict__ st0,
    float* __restrict__ sc1, float* __restrict__ st1,
    unsigned int* __restrict__ bar)
{
    __shared__ float Tsh[4][16][17];
    int bid = blockIdx.x, t = threadIdx.x;

    // ---------------- P1 ----------------
    if (bid < 256) {
        int bt = bid >> 4, it = bid & 15;
        int ii = it * 16 + (t & 15), b = bt * 16 + (t >> 4);
        float out[12];
        basis_eval(x[(size_t)b * 256 + ii], grid0, ii, out);
        out[9] = 0.f; out[10] = 0.f; out[11] = 0.f;
        store_rec12(bas9_0 + ((size_t)b * 256 + ii) * 12, out);
    } else {
        for (int id = bid - 256; id < 1024; id += 768) {
            if (id < 512) merge_body(coef0, ssp0, sb0, wc9_0, id * 256 + t);
            else          merge_body(coef1, ssp1, sb1, wc9_1, (id - 512) * 256 + t);
        }
    }
    gsync(bar, 1 * NB);

    // ---------------- P2 ----------------
    if (bid < 512) {
        gemm0_fused(wc9_0, bas9_0, bias0, grid1, bas9_1, bid, Tsh);
    } else {
        int r = bid - 512;   // og in [0,64), ch in [0,8)
        stats_body<256, 512>(bas9_0, wc9_0, spart0, r >> 3, r & 7, 0);
    }
    gsync(bar, 2 * NB);

    // ---------------- P3 ----------------
    if (bid < 256) {
        gemm1_fused(bas9_1, wc9_1, bias1, x2, bid, Tsh);
    } else if (bid < 768) {
        int r = bid - 256;   // og in [0,32), ch in [0,8), isp in {0,1}
        int og = r >> 4, rem = r & 15;
        stats_body<512, 256>(bas9_1, wc9_1, spart1, og, rem & 7, rem >> 3);
    } else {
        statsfin_body(spart0, grid0, sc0, st0, 131072, (bid - 768) * 256 + t);
    }
    gsync(bar, 3 * NB);

    // ---------------- P4 ----------------
    if (bid < 256)
        statsfin_body(spart0, grid0, sc0, st0, 131072, (256 + bid) * 256 + t);
    if (bid < 512)
        statsfin_body(spart1, grid1, sc1, st1, 131072, bid * 256 + t);
}

// ---------------------------------------------------------------------------
extern "C" void kernel_launch(void* const* d_in, const int* in_sizes, int n_in,
                              void* d_out, int out_size, void* d_ws, size_t ws_size,
                              hipStream_t stream)
{
    const float* x     = (const float*)d_in[0];
    const float* grid0 = (const float*)d_in[1];
    const float* coef0 = (const float*)d_in[2];
    const float* sb0   = (const float*)d_in[3];
    const float* ssp0  = (const float*)d_in[4];
    const float* bias0 = (const float*)d_in[5];
    const float* grid1 = (const float*)d_in[6];
    const float* coef1 = (const float*)d_in[7];
    const float* sb1   = (const float*)d_in[8];
    const float* ssp1  = (const float*)d_in[9];
    const float* bias1 = (const float*)d_in[10];

    float* out = (float*)d_out;
    float* x2  = out;                 // (256,256)
    float* sc0 = out + 65536;         // (512,256)
    float* st0 = out + 196608;        // (512,256)
    float* sc1 = out + 327680;        // (256,512)
    float* st1 = out + 458752;        // (256,512)

    // Workspace (~36 MB, all disjoint)
    char* w = (char*)d_ws;
    unsigned short* wc9_0  = (unsigned short*)w; w += (size_t)512 * 3072 * 2;
    unsigned short* wc9_1  = (unsigned short*)w; w += (size_t)256 * 6144 * 2;
    unsigned short* bas9_0 = (unsigned short*)w; w += (size_t)256 * 3072 * 2;
    unsigned short* bas9_1 = (unsigned short*)w; w += (size_t)256 * 6144 * 2;
    float* spart0 = (float*)w; w += (size_t)8 * 3 * 131072 * 4;
    float* spart1 = (float*)w; w += (size_t)8 * 3 * 131072 * 4;
    unsigned int* bar = (unsigned int*)w; w += 256;

    // Zero the barrier counter (in-graph, replayed every call).
    hipMemsetAsync((void*)bar, 0, 64, stream);

    kan_mono<<<NB, 256, 0, stream>>>(
        coef0, ssp0, sb0, wc9_0,
        coef1, ssp1, sb1, wc9_1,
        x, grid0, bas9_0,
        bias0, grid1, bas9_1,
        spart0, spart1,
        bias1, x2,
        sc0, st0, sc1, st1,
        bar);
}

// Round 15
// 120.594 us; speedup vs baseline: 4.9520x; 4.9520x over previous
//
#include <hip/hip_runtime.h>
#include <math.h>

constexpr int BATCH = 256;

typedef short short8 __attribute__((ext_vector_type(8)));
typedef float f32x4 __attribute__((ext_vector_type(4)));

// ---------------------------------------------------------------------------
// bf16 helpers (RNE)
// ---------------------------------------------------------------------------
__device__ __forceinline__ unsigned short f2bf(float f) {
    unsigned int u = __float_as_uint(f);
    u += 0x7FFFu + ((u >> 16) & 1u);
    return (unsigned short)(u >> 16);
}
__device__ __forceinline__ float bf2f(unsigned short h) {
    return __uint_as_float(((unsigned int)h) << 16);
}
__device__ __forceinline__ unsigned int pack2(float a, float b) {
    return (unsigned int)f2bf(a) | ((unsigned int)f2bf(b) << 16);
}

// ---------------------------------------------------------------------------
// basis_eval: 8 cubic B-spline values + silu. out[0..7]=basis, out[8]=silu.
// ---------------------------------------------------------------------------
__device__ __forceinline__ void basis_eval(
    float x, const float* __restrict__ grid, int ii, float out[9])
{
    float g[6];
#pragma unroll
    for (int k = 0; k < 6; ++k) g[k] = grid[(size_t)ii * 6 + k];
    float h = (g[5] - g[0]) * 0.2f;

    float t[12];
    t[0] = g[0] - 3.f * h; t[1] = g[0] - 2.f * h; t[2] = g[0] - h;
#pragma unroll
    for (int k = 0; k < 6; ++k) t[3 + k] = g[k];
    t[9] = g[5] + h; t[10] = g[5] + 2.f * h; t[11] = g[5] + 3.f * h;

    float Bv[11];
#pragma unroll
    for (int j = 0; j < 11; ++j)
        Bv[j] = (x >= t[j] && x < t[j + 1]) ? 1.0f : 0.0f;

#pragma unroll
    for (int d = 1; d <= 3; ++d) {
#pragma unroll
        for (int j = 0; j + d < 11; ++j) {
            float left  = __fdividef(x - t[j],         t[j + d] - t[j]);
            float right = __fdividef(t[j + d + 1] - x, t[j + d + 1] - t[j + 1]);
            Bv[j] = left * Bv[j] + right * Bv[j + 1];
        }
    }

#pragma unroll
    for (int k = 0; k < 8; ++k) out[k] = Bv[k];
    out[8] = __fdividef(x, 1.0f + __expf(-x));
}

// store 12 floats (last 3 zero) as a 24B bf16 record at rec (8B aligned)
__device__ __forceinline__ void store_rec12(unsigned short* rec, const float v[12])
{
    unsigned int u[6];
#pragma unroll
    for (int j = 0; j < 6; ++j)
        u[j] = pack2(v[2 * j], v[2 * j + 1]);
    uint2* p = (uint2*)rec;
    p[0] = make_uint2(u[0], u[1]);
    p[1] = make_uint2(u[2], u[3]);
    p[2] = make_uint2(u[4], u[5]);
}

// ---------------------------------------------------------------------------
// merge: writes gemm pack record (24B at wc9) AND stats planes (wpA/wpB/wpC).
// ---------------------------------------------------------------------------
__device__ __forceinline__ void merge_body(
    const float* __restrict__ coef, const float* __restrict__ ssp,
    const float* __restrict__ sb, unsigned short* __restrict__ wc9,
    uint2* __restrict__ wpA, uint2* __restrict__ wpB,
    unsigned short* __restrict__ wpC, int s)
{
    float sspv = ssp[s], sbv = sb[s];
    const float4* c = (const float4*)(coef + (size_t)s * 8);
    float4 c0 = c[0], c1 = c[1];
    float v[12] = { sspv * c0.x, sspv * c0.y, sspv * c0.z, sspv * c0.w,
                    sspv * c1.x, sspv * c1.y, sspv * c1.z, sspv * c1.w,
                    sbv, 0.f, 0.f, 0.f };
    store_rec12(wc9 + (size_t)s * 12, v);
    wpA[s] = make_uint2(pack2(v[0], v[1]), pack2(v[2], v[3]));
    wpB[s] = make_uint2(pack2(v[4], v[5]), pack2(v[6], v[7]));
    wpC[s] = f2bf(sbv);
}

// ---------------------------------------------------------------------------
// gemm0 fused (512 tasks = 32 mt x 16 nt): one 16x16 tile (m=ii, n=b),
// 4 waves split K (K2=3072 -> 24-MFMA chain each), LDS reduce.
// Epilogue: xmid = D + bias0 -> basis_eval -> bas9_1 pack + layer1 planes.
// ---------------------------------------------------------------------------
__device__ __forceinline__ void gemm0_fused(
    const unsigned short* __restrict__ wc9_0, const unsigned short* __restrict__ bas9_0,
    const float* __restrict__ bias0, const float* __restrict__ grid1,
    unsigned short* __restrict__ bas9_1,
    uint2* __restrict__ bpA1, uint2* __restrict__ bpB1,
    unsigned short* __restrict__ bpC1, int bid, float (*T)[16][17])
{
    constexpr int K2 = 3072, KW = K2 / 4;
    int mt = bid >> 4, nt = bid & 15;
    int t = threadIdx.x, l = t & 63, w = t >> 6;
    int m0 = mt * 16;            // ii base (layer-1 input)
    int n0 = nt * 16;            // b base

    const unsigned short* pa = wc9_0  + (size_t)(m0 + (l & 15)) * K2 + w * KW + ((l >> 4) * 8);
    const unsigned short* pb = bas9_0 + (size_t)(n0 + (l & 15)) * K2 + w * KW + ((l >> 4) * 8);

    f32x4 acc = {0.f, 0.f, 0.f, 0.f};
#pragma unroll 8
    for (int kk = 0; kk < KW / 32; ++kk) {   // 24 steps
        short8 av = *(const short8*)pa; pa += 32;
        short8 bv = *(const short8*)pb; pb += 32;
        acc = __builtin_amdgcn_mfma_f32_16x16x32_bf16(av, bv, acc, 0, 0, 0);
    }

#pragma unroll
    for (int r = 0; r < 4; ++r)
        T[w][(l >> 4) * 4 + r][l & 15] = acc[r];   // [m_loc][n_loc]
    __syncthreads();

    int ii_loc = t & 15, b_loc = t >> 4;     // thread owns one element
    float d = T[0][ii_loc][b_loc] + T[1][ii_loc][b_loc]
            + T[2][ii_loc][b_loc] + T[3][ii_loc][b_loc];
    int ii = m0 + ii_loc;
    float xv = d + bias0[ii];
    float out[12];
    basis_eval(xv, grid1, ii, out);
    out[9] = 0.f; out[10] = 0.f; out[11] = 0.f;
    size_t p = (size_t)(n0 + b_loc) * 512 + ii;
    store_rec12(bas9_1 + p * 12, out);
    bpA1[p] = make_uint2(pack2(out[0], out[1]), pack2(out[2], out[3]));
    bpB1[p] = make_uint2(pack2(out[4], out[5]), pack2(out[6], out[7]));
    bpC1[p] = f2bf(out[8]);
    __syncthreads();
}

// ---------------------------------------------------------------------------
// gemm1 fused (256 tasks = 16 mt x 16 nt): one 16x16 tile (m=b, n=o),
// 4 waves split K (K2=6144 -> 48-MFMA chain each), LDS reduce.
// Epilogue: x2[b][o] = D + bias1[o].
// ---------------------------------------------------------------------------
__device__ __forceinline__ void gemm1_fused(
    const unsigned short* __restrict__ bas9_1, const unsigned short* __restrict__ wc9_1,
    const float* __restrict__ bias1, float* __restrict__ x2, int bid, float (*T)[16][17])
{
    constexpr int K2 = 6144, KW = K2 / 4;
    int mt = bid >> 4, nt = bid & 15;
    int t = threadIdx.x, l = t & 63, w = t >> 6;
    int m0 = mt * 16;            // b base
    int n0 = nt * 16;            // o base

    const unsigned short* pa = bas9_1 + (size_t)(m0 + (l & 15)) * K2 + w * KW + ((l >> 4) * 8);
    const unsigned short* pb = wc9_1  + (size_t)(n0 + (l & 15)) * K2 + w * KW + ((l >> 4) * 8);

    f32x4 acc = {0.f, 0.f, 0.f, 0.f};
#pragma unroll 8
    for (int kk = 0; kk < KW / 32; ++kk) {   // 48 steps
        short8 av = *(const short8*)pa; pa += 32;
        short8 bv = *(const short8*)pb; pb += 32;
        acc = __builtin_amdgcn_mfma_f32_16x16x32_bf16(av, bv, acc, 0, 0, 0);
    }

#pragma unroll
    for (int r = 0; r < 4; ++r)
        T[w][(l >> 4) * 4 + r][l & 15] = acc[r];   // [b_loc][o_loc]
    __syncthreads();

    int o_loc = t & 15, b_loc = t >> 4;
    float d = T[0][b_loc][o_loc] + T[1][b_loc][o_loc]
            + T[2][b_loc][o_loc] + T[3][b_loc][o_loc];
    int o = n0 + o_loc;
    x2[(size_t)(m0 + b_loc) * 256 + o] = d + bias1[o];
}

// ---------------------------------------------------------------------------
// stats finalize for one flat output s (fixed summation order -> deterministic)
// ---------------------------------------------------------------------------
__device__ __forceinline__ void statsfin_body(
    const float* __restrict__ spart, const float* __restrict__ grid,
    float* __restrict__ sc, float* __restrict__ st, int size, int s)
{
    float ab = 0.f, sm = 0.f, sq = 0.f;
#pragma unroll
    for (int k = 0; k < 8; ++k) {
        size_t base = (size_t)k * 3 * (size_t)size;
        ab += spart[base + s];
        sm += spart[base + (size_t)size + s];
        sq += spart[base + 2 * (size_t)size + s];
    }
    float range = grid[(size_t)s * 6 + 5] - grid[(size_t)s * 6 + 0] + 1e-4f;
    sc[s] = (ab * (1.0f / BATCH)) / range;
    float var = (sq - sm * sm * (1.0f / BATCH)) * (1.0f / (BATCH - 1));
    st[s] = sqrtf(fmaxf(var, 0.0f));
}

// ---------------------------------------------------------------------------
// stats sweep (plane layout): thread = ii (ii = isp*256+t), 8 o's in regs,
// BCH=32 b's per block. All loads dense (uint2/uint2/ushort planes).
// After spart write: one agent-scope ticket RMW per block; last of the og's
// NCH blocks finalizes that og's sc/st rows inline (fixed order).
// ---------------------------------------------------------------------------
template <int I, int O, int NCH>
__device__ __forceinline__ void stats_body(
    const uint2* __restrict__ bpA, const uint2* __restrict__ bpB,
    const unsigned short* __restrict__ bpC,
    const uint2* __restrict__ wpA, const uint2* __restrict__ wpB,
    const unsigned short* __restrict__ wpC,
    float* __restrict__ spart, unsigned int* __restrict__ ticket,
    const float* __restrict__ grid, float* __restrict__ sc, float* __restrict__ st,
    int og, int ch, int isp)
{
    constexpr int OTB = 8, BCH = 32;
    const size_t OI = (size_t)O * I;
    int t = threadIdx.x;
    int ii = isp * 256 + t;

    float wcr[OTB][9];
#pragma unroll
    for (int o = 0; o < OTB; ++o) {
        size_t s = (size_t)(og * OTB + o) * I + ii;
        uint2 qa = wpA[s], qb = wpB[s];
        wcr[o][0] = bf2f((unsigned short)qa.x);
        wcr[o][1] = bf2f((unsigned short)(qa.x >> 16));
        wcr[o][2] = bf2f((unsigned short)qa.y);
        wcr[o][3] = bf2f((unsigned short)(qa.y >> 16));
        wcr[o][4] = bf2f((unsigned short)qb.x);
        wcr[o][5] = bf2f((unsigned short)(qb.x >> 16));
        wcr[o][6] = bf2f((unsigned short)qb.y);
        wcr[o][7] = bf2f((unsigned short)(qb.y >> 16));
        wcr[o][8] = bf2f(wpC[s]);
    }

    float aab[OTB], asum[OTB], asq[OTB];
#pragma unroll
    for (int o = 0; o < OTB; ++o) { aab[o] = 0.f; asum[o] = 0.f; asq[o] = 0.f; }

    for (int bl = 0; bl < BCH; ++bl) {
        int b = ch * BCH + bl;
        size_t p = (size_t)b * I + ii;
        uint2 qa = bpA[p], qb = bpB[p];
        float f0 = bf2f((unsigned short)qa.x), f1 = bf2f((unsigned short)(qa.x >> 16));
        float f2 = bf2f((unsigned short)qa.y), f3 = bf2f((unsigned short)(qa.y >> 16));
        float f4 = bf2f((unsigned short)qb.x), f5 = bf2f((unsigned short)(qb.x >> 16));
        float f6 = bf2f((unsigned short)qb.y), f7 = bf2f((unsigned short)(qb.y >> 16));
        float f8 = bf2f(bpC[p]);
#pragma unroll
        for (int o = 0; o < OTB; ++o) {
            float y = wcr[o][8] * f8;
            y = fmaf(f0, wcr[o][0], y); y = fmaf(f1, wcr[o][1], y);
            y = fmaf(f2, wcr[o][2], y); y = fmaf(f3, wcr[o][3], y);
            y = fmaf(f4, wcr[o][4], y); y = fmaf(f5, wcr[o][5], y);
            y = fmaf(f6, wcr[o][6], y); y = fmaf(f7, wcr[o][7], y);
            aab[o] += fabsf(y);
            asum[o] += y;
            asq[o] = fmaf(y, y, asq[o]);
        }
    }

    size_t cb = (size_t)ch * 3 * OI;
#pragma unroll
    for (int o = 0; o < OTB; ++o) {
        size_t s = (size_t)(og * OTB + o) * I + ii;
        spart[cb + s]          = aab[o];
        spart[cb + OI + s]     = asum[o];
        spart[cb + 2 * OI + s] = asq[o];
    }

    // ---- ticket: last block of this og finalizes its rows ----
    __shared__ unsigned int oldv;
    __syncthreads();   // all spart stores drained (compiler waitcnt) before RMW
    if (t == 0)
        oldv = __hip_atomic_fetch_add(&ticket[og], 1u, __ATOMIC_ACQ_REL,
                                      __HIP_MEMORY_SCOPE_AGENT);
    __syncthreads();
    if (oldv == (unsigned int)(NCH - 1)) {
        constexpr int SPAN = OTB * I;          // outputs per og
        for (int k = t; k < SPAN; k += 256)
            statsfin_body(spart, grid, sc, st, (int)OI, og * SPAN + k);
    }
}

// ---------------------------------------------------------------------------
// K1: merge0(512) | merge1(512) | basis0(256, ii-lane-fast)  -> 1280 blocks
// ---------------------------------------------------------------------------
__global__ __launch_bounds__(256) void k1_prep(
    const float* __restrict__ coef0, const float* __restrict__ ssp0,
    const float* __restrict__ sb0,   unsigned short* __restrict__ wc9_0,
    uint2* __restrict__ wpA0, uint2* __restrict__ wpB0, unsigned short* __restrict__ wpC0,
    const float* __restrict__ coef1, const float* __restrict__ ssp1,
    const float* __restrict__ sb1,   unsigned short* __restrict__ wc9_1,
    uint2* __restrict__ wpA1, uint2* __restrict__ wpB1, unsigned short* __restrict__ wpC1,
    const float* __restrict__ x, const float* __restrict__ grid0,
    unsigned short* __restrict__ bas9_0,
    uint2* __restrict__ bpA0, uint2* __restrict__ bpB0, unsigned short* __restrict__ bpC0)
{
    int bid = blockIdx.x, t = threadIdx.x;
    if (bid < 512)  { merge_body(coef0, ssp0, sb0, wc9_0, wpA0, wpB0, wpC0, bid * 256 + t); return; }
    if (bid < 1024) { merge_body(coef1, ssp1, sb1, wc9_1, wpA1, wpB1, wpC1, (bid - 512) * 256 + t); return; }
    int tile = bid - 1024;                 // 16 bt x 16 it
    int bt = tile >> 4, it = tile & 15;
    int ii = it * 16 + (t & 15), b = bt * 16 + (t >> 4);
    float out[12];
    basis_eval(x[(size_t)b * 256 + ii], grid0, ii, out);
    out[9] = 0.f; out[10] = 0.f; out[11] = 0.f;
    size_t p = (size_t)b * 256 + ii;
    store_rec12(bas9_0 + p * 12, out);
    bpA0[p] = make_uint2(pack2(out[0], out[1]), pack2(out[2], out[3]));
    bpB0[p] = make_uint2(pack2(out[4], out[5]), pack2(out[6], out[7]));
    bpC0[p] = f2bf(out[8]);
}

// ---------------------------------------------------------------------------
// K2: gemm0-fused(512) | stats0(512, fused fin)              -> 1024 blocks
// ---------------------------------------------------------------------------
__global__ __launch_bounds__(256) void k2_sweep0(
    const unsigned short* __restrict__ wc9_0, const unsigned short* __restrict__ bas9_0,
    const float* __restrict__ bias0, const float* __restrict__ grid1,
    unsigned short* __restrict__ bas9_1,
    uint2* __restrict__ bpA1, uint2* __restrict__ bpB1, unsigned short* __restrict__ bpC1,
    const uint2* __restrict__ bpA0, const uint2* __restrict__ bpB0,
    const unsigned short* __restrict__ bpC0,
    const uint2* __restrict__ wpA0, const uint2* __restrict__ wpB0,
    const unsigned short* __restrict__ wpC0,
    float* __restrict__ spart0, unsigned int* __restrict__ ticket0,
    const float* __restrict__ grid0, float* __restrict__ sc0, float* __restrict__ st0)
{
    __shared__ float Tsh[4][16][17];
    int bid = blockIdx.x;
    if (bid < 512) {
        gemm0_fused(wc9_0, bas9_0, bias0, grid1, bas9_1, bpA1, bpB1, bpC1, bid, Tsh);
    } else {
        int r = bid - 512;   // og in [0,64), ch in [0,8)
        stats_body<256, 512, 8>(bpA0, bpB0, bpC0, wpA0, wpB0, wpC0,
                                spart0, ticket0, grid0, sc0, st0,
                                r >> 3, r & 7, 0);
    }
}

// ---------------------------------------------------------------------------
// K3: gemm1-fused(256) | stats1(512, fused fin)              -> 768 blocks
// ---------------------------------------------------------------------------
__global__ __launch_bounds__(256) void k3_sweep1(
    const unsigned short* __restrict__ bas9_1, const unsigned short* __restrict__ wc9_1,
    const float* __restrict__ bias1, float* __restrict__ x2,
    const uint2* __restrict__ bpA1, const uint2* __restrict__ bpB1,
    const unsigned short* __restrict__ bpC1,
    const uint2* __restrict__ wpA1, const uint2* __restrict__ wpB1,
    const unsigned short* __restrict__ wpC1,
    float* __restrict__ spart1, unsigned int* __restrict__ ticket1,
    const float* __restrict__ grid1, float* __restrict__ sc1, float* __restrict__ st1)
{
    __shared__ float Tsh[4][16][17];
    int bid = blockIdx.x;
    if (bid < 256) {
        gemm1_fused(bas9_1, wc9_1, bias1, x2, bid, Tsh);
    } else {
        int r = bid - 256;   // og in [0,32), ch in [0,8), isp in {0,1}
        int og = r >> 4, rem = r & 15;
        stats_body<512, 256, 16>(bpA1, bpB1, bpC1, wpA1, wpB1, wpC1,
                                 spart1, ticket1, grid1, sc1, st1,
                                 og, rem & 7, rem >> 3);
    }
}

// ---------------------------------------------------------------------------
extern "C" void kernel_launch(void* const* d_in, const int* in_sizes, int n_in,
                              void* d_out, int out_size, void* d_ws, size_t ws_size,
                              hipStream_t stream)
{
    const float* x     = (const float*)d_in[0];
    const float* grid0 = (const float*)d_in[1];
    const float* coef0 = (const float*)d_in[2];
    const float* sb0   = (const float*)d_in[3];
    const float* ssp0  = (const float*)d_in[4];
    const float* bias0 = (const float*)d_in[5];
    const float* grid1 = (const float*)d_in[6];
    const float* coef1 = (const float*)d_in[7];
    const float* sb1   = (const float*)d_in[8];
    const float* ssp1  = (const float*)d_in[9];
    const float* bias1 = (const float*)d_in[10];

    float* out = (float*)d_out;
    float* x2  = out;                 // (256,256)
    float* sc0 = out + 65536;         // (512,256)
    float* st0 = out + 196608;        // (512,256)
    float* sc1 = out + 327680;        // (256,512)
    float* st1 = out + 458752;        // (256,512)

    // Workspace (~44 MB, all disjoint)
    char* w = (char*)d_ws;
    unsigned short* wc9_0  = (unsigned short*)w; w += (size_t)512 * 3072 * 2;
    unsigned short* wc9_1  = (unsigned short*)w; w += (size_t)256 * 6144 * 2;
    unsigned short* bas9_0 = (unsigned short*)w; w += (size_t)256 * 3072 * 2;
    unsigned short* bas9_1 = (unsigned short*)w; w += (size_t)256 * 6144 * 2;
    uint2* wpA0 = (uint2*)w; w += (size_t)131072 * 8;
    uint2* wpB0 = (uint2*)w; w += (size_t)131072 * 8;
    uint2* wpA1 = (uint2*)w; w += (size_t)131072 * 8;
    uint2* wpB1 = (uint2*)w; w += (size_t)131072 * 8;
    uint2* bpA0 = (uint2*)w; w += (size_t)65536 * 8;
    uint2* bpB0 = (uint2*)w; w += (size_t)65536 * 8;
    uint2* bpA1 = (uint2*)w; w += (size_t)131072 * 8;
    uint2* bpB1 = (uint2*)w; w += (size_t)131072 * 8;
    unsigned short* wpC0 = (unsigned short*)w; w += (size_t)131072 * 2;
    unsigned short* wpC1 = (unsigned short*)w; w += (size_t)131072 * 2;
    unsigned short* bpC0 = (unsigned short*)w; w += (size_t)65536 * 2;
    unsigned short* bpC1 = (unsigned short*)w; w += (size_t)131072 * 2;
    float* spart0 = (float*)w; w += (size_t)8 * 3 * 131072 * 4;
    float* spart1 = (float*)w; w += (size_t)8 * 3 * 131072 * 4;
    unsigned int* ticket0 = (unsigned int*)w; w += 64 * 4;
    unsigned int* ticket1 = (unsigned int*)w; w += 64 * 4;

    // Zero ticket counters (in-graph, replayed every call).
    hipMemsetAsync((void*)ticket0, 0, 128 * 4, stream);

    k1_prep<<<1280, 256, 0, stream>>>(
        coef0, ssp0, sb0, wc9_0, wpA0, wpB0, wpC0,
        coef1, ssp1, sb1, wc9_1, wpA1, wpB1, wpC1,
        x, grid0, bas9_0, bpA0, bpB0, bpC0);

    k2_sweep0<<<1024, 256, 0, stream>>>(
        wc9_0, bas9_0, bias0, grid1, bas9_1, bpA1, bpB1, bpC1,
        bpA0, bpB0, bpC0, wpA0, wpB0, wpC0,
        spart0, ticket0, grid0, sc0, st0);

    k3_sweep1<<<768, 256, 0, stream>>>(
        bas9_1, wc9_1, bias1, x2,
        bpA1, bpB1, bpC1, wpA1, wpB1, wpC1,
        spart1, ticket1, grid1, sc1, st1);
}

// Round 16
// 71.852 us; speedup vs baseline: 8.3114x; 1.6784x over previous
//
#include <hip/hip_runtime.h>
#include <math.h>

constexpr int BATCH = 256;

typedef short short8 __attribute__((ext_vector_type(8)));
typedef float f32x4 __attribute__((ext_vector_type(4)));

// ---------------------------------------------------------------------------
// bf16 helpers (RNE)
// ---------------------------------------------------------------------------
__device__ __forceinline__ unsigned short f2bf(float f) {
    unsigned int u = __float_as_uint(f);
    u += 0x7FFFu + ((u >> 16) & 1u);
    return (unsigned short)(u >> 16);
}
__device__ __forceinline__ float bf2f(unsigned short h) {
    return __uint_as_float(((unsigned int)h) << 16);
}
__device__ __forceinline__ unsigned int pack2(float a, float b) {
    return (unsigned int)f2bf(a) | ((unsigned int)f2bf(b) << 16);
}

// ---------------------------------------------------------------------------
// basis_eval: 8 cubic B-spline values + silu. out[0..7]=basis, out[8]=silu.
// ---------------------------------------------------------------------------
__device__ __forceinline__ void basis_eval(
    float x, const float* __restrict__ grid, int ii, float out[9])
{
    float g[6];
#pragma unroll
    for (int k = 0; k < 6; ++k) g[k] = grid[(size_t)ii * 6 + k];
    float h = (g[5] - g[0]) * 0.2f;

    float t[12];
    t[0] = g[0] - 3.f * h; t[1] = g[0] - 2.f * h; t[2] = g[0] - h;
#pragma unroll
    for (int k = 0; k < 6; ++k) t[3 + k] = g[k];
    t[9] = g[5] + h; t[10] = g[5] + 2.f * h; t[11] = g[5] + 3.f * h;

    float Bv[11];
#pragma unroll
    for (int j = 0; j < 11; ++j)
        Bv[j] = (x >= t[j] && x < t[j + 1]) ? 1.0f : 0.0f;

#pragma unroll
    for (int d = 1; d <= 3; ++d) {
#pragma unroll
        for (int j = 0; j + d < 11; ++j) {
            float left  = __fdividef(x - t[j],         t[j + d] - t[j]);
            float right = __fdividef(t[j + d + 1] - x, t[j + d + 1] - t[j + 1]);
            Bv[j] = left * Bv[j] + right * Bv[j + 1];
        }
    }

#pragma unroll
    for (int k = 0; k < 8; ++k) out[k] = Bv[k];
    out[8] = __fdividef(x, 1.0f + __expf(-x));
}

// store 12 floats (last 3 zero) as a 24B bf16 record at rec (8B aligned)
__device__ __forceinline__ void store_rec12(unsigned short* rec, const float v[12])
{
    unsigned int u[6];
#pragma unroll
    for (int j = 0; j < 6; ++j)
        u[j] = pack2(v[2 * j], v[2 * j + 1]);
    uint2* p = (uint2*)rec;
    p[0] = make_uint2(u[0], u[1]);
    p[1] = make_uint2(u[2], u[3]);
    p[2] = make_uint2(u[4], u[5]);
}

// ---------------------------------------------------------------------------
// merge: writes gemm pack record (24B at wc9) AND stats planes (wpA/wpB/wpC).
// ---------------------------------------------------------------------------
__device__ __forceinline__ void merge_body(
    const float* __restrict__ coef, const float* __restrict__ ssp,
    const float* __restrict__ sb, unsigned short* __restrict__ wc9,
    uint2* __restrict__ wpA, uint2* __restrict__ wpB,
    unsigned short* __restrict__ wpC, int s)
{
    float sspv = ssp[s], sbv = sb[s];
    const float4* c = (const float4*)(coef + (size_t)s * 8);
    float4 c0 = c[0], c1 = c[1];
    float v[12] = { sspv * c0.x, sspv * c0.y, sspv * c0.z, sspv * c0.w,
                    sspv * c1.x, sspv * c1.y, sspv * c1.z, sspv * c1.w,
                    sbv, 0.f, 0.f, 0.f };
    store_rec12(wc9 + (size_t)s * 12, v);
    wpA[s] = make_uint2(pack2(v[0], v[1]), pack2(v[2], v[3]));
    wpB[s] = make_uint2(pack2(v[4], v[5]), pack2(v[6], v[7]));
    wpC[s] = f2bf(sbv);
}

// ---------------------------------------------------------------------------
// gemm0 fused (512 tasks = 32 mt x 16 nt): one 16x16 tile (m=ii, n=b),
// 4 waves split K (K2=3072 -> 24-MFMA chain each), LDS reduce.
// Epilogue: xmid = D + bias0 -> basis_eval -> bas9_1 pack + layer1 planes.
// ---------------------------------------------------------------------------
__device__ __forceinline__ void gemm0_fused(
    const unsigned short* __restrict__ wc9_0, const unsigned short* __restrict__ bas9_0,
    const float* __restrict__ bias0, const float* __restrict__ grid1,
    unsigned short* __restrict__ bas9_1,
    uint2* __restrict__ bpA1, uint2* __restrict__ bpB1,
    unsigned short* __restrict__ bpC1, int bid, float (*T)[16][17])
{
    constexpr int K2 = 3072, KW = K2 / 4;
    int mt = bid >> 4, nt = bid & 15;
    int t = threadIdx.x, l = t & 63, w = t >> 6;
    int m0 = mt * 16;            // ii base (layer-1 input)
    int n0 = nt * 16;            // b base

    const unsigned short* pa = wc9_0  + (size_t)(m0 + (l & 15)) * K2 + w * KW + ((l >> 4) * 8);
    const unsigned short* pb = bas9_0 + (size_t)(n0 + (l & 15)) * K2 + w * KW + ((l >> 4) * 8);

    f32x4 acc = {0.f, 0.f, 0.f, 0.f};
#pragma unroll 8
    for (int kk = 0; kk < KW / 32; ++kk) {   // 24 steps
        short8 av = *(const short8*)pa; pa += 32;
        short8 bv = *(const short8*)pb; pb += 32;
        acc = __builtin_amdgcn_mfma_f32_16x16x32_bf16(av, bv, acc, 0, 0, 0);
    }

#pragma unroll
    for (int r = 0; r < 4; ++r)
        T[w][(l >> 4) * 4 + r][l & 15] = acc[r];   // [m_loc][n_loc]
    __syncthreads();

    int ii_loc = t & 15, b_loc = t >> 4;     // thread owns one element
    float d = T[0][ii_loc][b_loc] + T[1][ii_loc][b_loc]
            + T[2][ii_loc][b_loc] + T[3][ii_loc][b_loc];
    int ii = m0 + ii_loc;
    float xv = d + bias0[ii];
    float out[12];
    basis_eval(xv, grid1, ii, out);
    out[9] = 0.f; out[10] = 0.f; out[11] = 0.f;
    size_t p = (size_t)(n0 + b_loc) * 512 + ii;
    store_rec12(bas9_1 + p * 12, out);
    bpA1[p] = make_uint2(pack2(out[0], out[1]), pack2(out[2], out[3]));
    bpB1[p] = make_uint2(pack2(out[4], out[5]), pack2(out[6], out[7]));
    bpC1[p] = f2bf(out[8]);
    __syncthreads();
}

// ---------------------------------------------------------------------------
// gemm1 fused (256 tasks = 16 mt x 16 nt): one 16x16 tile (m=b, n=o),
// 4 waves split K (K2=6144 -> 48-MFMA chain each), LDS reduce.
// Epilogue: x2[b][o] = D + bias1[o].
// ---------------------------------------------------------------------------
__device__ __forceinline__ void gemm1_fused(
    const unsigned short* __restrict__ bas9_1, const unsigned short* __restrict__ wc9_1,
    const float* __restrict__ bias1, float* __restrict__ x2, int bid, float (*T)[16][17])
{
    constexpr int K2 = 6144, KW = K2 / 4;
    int mt = bid >> 4, nt = bid & 15;
    int t = threadIdx.x, l = t & 63, w = t >> 6;
    int m0 = mt * 16;            // b base
    int n0 = nt * 16;            // o base

    const unsigned short* pa = bas9_1 + (size_t)(m0 + (l & 15)) * K2 + w * KW + ((l >> 4) * 8);
    const unsigned short* pb = wc9_1  + (size_t)(n0 + (l & 15)) * K2 + w * KW + ((l >> 4) * 8);

    f32x4 acc = {0.f, 0.f, 0.f, 0.f};
#pragma unroll 8
    for (int kk = 0; kk < KW / 32; ++kk) {   // 48 steps
        short8 av = *(const short8*)pa; pa += 32;
        short8 bv = *(const short8*)pb; pb += 32;
        acc = __builtin_amdgcn_mfma_f32_16x16x32_bf16(av, bv, acc, 0, 0, 0);
    }

#pragma unroll
    for (int r = 0; r < 4; ++r)
        T[w][(l >> 4) * 4 + r][l & 15] = acc[r];   // [b_loc][o_loc]
    __syncthreads();

    int o_loc = t & 15, b_loc = t >> 4;
    float d = T[0][b_loc][o_loc] + T[1][b_loc][o_loc]
            + T[2][b_loc][o_loc] + T[3][b_loc][o_loc];
    int o = n0 + o_loc;
    x2[(size_t)(m0 + b_loc) * 256 + o] = d + bias1[o];
}

// ---------------------------------------------------------------------------
// stats sweep (plane layout): thread = ii (ii = isp*256+t), 8 o's in regs,
// BCH=32 b's per block. All loads dense (uint2/uint2/ushort planes).
// spart: [8][3][O*I]. NO atomics.
// ---------------------------------------------------------------------------
template <int I, int O>
__device__ __forceinline__ void stats_body(
    const uint2* __restrict__ bpA, const uint2* __restrict__ bpB,
    const unsigned short* __restrict__ bpC,
    const uint2* __restrict__ wpA, const uint2* __restrict__ wpB,
    const unsigned short* __restrict__ wpC,
    float* __restrict__ spart, int og, int ch, int isp)
{
    constexpr int OTB = 8, BCH = 32;
    const size_t OI = (size_t)O * I;
    int t = threadIdx.x;
    int ii = isp * 256 + t;

    float wcr[OTB][9];
#pragma unroll
    for (int o = 0; o < OTB; ++o) {
        size_t s = (size_t)(og * OTB + o) * I + ii;
        uint2 qa = wpA[s], qb = wpB[s];
        wcr[o][0] = bf2f((unsigned short)qa.x);
        wcr[o][1] = bf2f((unsigned short)(qa.x >> 16));
        wcr[o][2] = bf2f((unsigned short)qa.y);
        wcr[o][3] = bf2f((unsigned short)(qa.y >> 16));
        wcr[o][4] = bf2f((unsigned short)qb.x);
        wcr[o][5] = bf2f((unsigned short)(qb.x >> 16));
        wcr[o][6] = bf2f((unsigned short)qb.y);
        wcr[o][7] = bf2f((unsigned short)(qb.y >> 16));
        wcr[o][8] = bf2f(wpC[s]);
    }

    float aab[OTB], asum[OTB], asq[OTB];
#pragma unroll
    for (int o = 0; o < OTB; ++o) { aab[o] = 0.f; asum[o] = 0.f; asq[o] = 0.f; }

    for (int bl = 0; bl < BCH; ++bl) {
        int b = ch * BCH + bl;
        size_t p = (size_t)b * I + ii;
        uint2 qa = bpA[p], qb = bpB[p];
        float f0 = bf2f((unsigned short)qa.x), f1 = bf2f((unsigned short)(qa.x >> 16));
        float f2 = bf2f((unsigned short)qa.y), f3 = bf2f((unsigned short)(qa.y >> 16));
        float f4 = bf2f((unsigned short)qb.x), f5 = bf2f((unsigned short)(qb.x >> 16));
        float f6 = bf2f((unsigned short)qb.y), f7 = bf2f((unsigned short)(qb.y >> 16));
        float f8 = bf2f(bpC[p]);
#pragma unroll
        for (int o = 0; o < OTB; ++o) {
            float y = wcr[o][8] * f8;
            y = fmaf(f0, wcr[o][0], y); y = fmaf(f1, wcr[o][1], y);
            y = fmaf(f2, wcr[o][2], y); y = fmaf(f3, wcr[o][3], y);
            y = fmaf(f4, wcr[o][4], y); y = fmaf(f5, wcr[o][5], y);
            y = fmaf(f6, wcr[o][6], y); y = fmaf(f7, wcr[o][7], y);
            aab[o] += fabsf(y);
            asum[o] += y;
            asq[o] = fmaf(y, y, asq[o]);
        }
    }

    size_t cb = (size_t)ch * 3 * OI;
#pragma unroll
    for (int o = 0; o < OTB; ++o) {
        size_t s = (size_t)(og * OTB + o) * I + ii;
        spart[cb + s]          = aab[o];
        spart[cb + OI + s]     = asum[o];
        spart[cb + 2 * OI + s] = asq[o];
    }
}

__device__ __forceinline__ void statsfin_body(
    const float* __restrict__ spart, const float* __restrict__ grid,
    float* __restrict__ sc, float* __restrict__ st, int size, int s)
{
    float ab = 0.f, sm = 0.f, sq = 0.f;
#pragma unroll
    for (int k = 0; k < 8; ++k) {
        size_t base = (size_t)k * 3 * (size_t)size;
        ab += spart[base + s];
        sm += spart[base + (size_t)size + s];
        sq += spart[base + 2 * (size_t)size + s];
    }
    float range = grid[(size_t)s * 6 + 5] - grid[(size_t)s * 6 + 0] + 1e-4f;
    sc[s] = (ab * (1.0f / BATCH)) / range;
    float var = (sq - sm * sm * (1.0f / BATCH)) * (1.0f / (BATCH - 1));
    st[s] = sqrtf(fmaxf(var, 0.0f));
}

// ---------------------------------------------------------------------------
// K1: merge0(512) | merge1(512) | basis0(256, ii-lane-fast)  -> 1280 blocks
// ---------------------------------------------------------------------------
__global__ __launch_bounds__(256) void k1_prep(
    const float* __restrict__ coef0, const float* __restrict__ ssp0,
    const float* __restrict__ sb0,   unsigned short* __restrict__ wc9_0,
    uint2* __restrict__ wpA0, uint2* __restrict__ wpB0, unsigned short* __restrict__ wpC0,
    const float* __restrict__ coef1, const float* __restrict__ ssp1,
    const float* __restrict__ sb1,   unsigned short* __restrict__ wc9_1,
    uint2* __restrict__ wpA1, uint2* __restrict__ wpB1, unsigned short* __restrict__ wpC1,
    const float* __restrict__ x, const float* __restrict__ grid0,
    unsigned short* __restrict__ bas9_0,
    uint2* __restrict__ bpA0, uint2* __restrict__ bpB0, unsigned short* __restrict__ bpC0)
{
    int bid = blockIdx.x, t = threadIdx.x;
    if (bid < 512)  { merge_body(coef0, ssp0, sb0, wc9_0, wpA0, wpB0, wpC0, bid * 256 + t); return; }
    if (bid < 1024) { merge_body(coef1, ssp1, sb1, wc9_1, wpA1, wpB1, wpC1, (bid - 512) * 256 + t); return; }
    int tile = bid - 1024;                 // 16 bt x 16 it
    int bt = tile >> 4, it = tile & 15;
    int ii = it * 16 + (t & 15), b = bt * 16 + (t >> 4);
    float out[12];
    basis_eval(x[(size_t)b * 256 + ii], grid0, ii, out);
    out[9] = 0.f; out[10] = 0.f; out[11] = 0.f;
    size_t p = (size_t)b * 256 + ii;
    store_rec12(bas9_0 + p * 12, out);
    bpA0[p] = make_uint2(pack2(out[0], out[1]), pack2(out[2], out[3]));
    bpB0[p] = make_uint2(pack2(out[4], out[5]), pack2(out[6], out[7]));
    bpC0[p] = f2bf(out[8]);
}

// ---------------------------------------------------------------------------
// K2: gemm0-fused(512) | stats0(512)                         -> 1024 blocks
// ---------------------------------------------------------------------------
__global__ __launch_bounds__(256) void k2_sweep0(
    const unsigned short* __restrict__ wc9_0, const unsigned short* __restrict__ bas9_0,
    const float* __restrict__ bias0, const float* __restrict__ grid1,
    unsigned short* __restrict__ bas9_1,
    uint2* __restrict__ bpA1, uint2* __restrict__ bpB1, unsigned short* __restrict__ bpC1,
    const uint2* __restrict__ bpA0, const uint2* __restrict__ bpB0,
    const unsigned short* __restrict__ bpC0,
    const uint2* __restrict__ wpA0, const uint2* __restrict__ wpB0,
    const unsigned short* __restrict__ wpC0,
    float* __restrict__ spart0)
{
    __shared__ float Tsh[4][16][17];
    int bid = blockIdx.x;
    if (bid < 512) {
        gemm0_fused(wc9_0, bas9_0, bias0, grid1, bas9_1, bpA1, bpB1, bpC1, bid, Tsh);
    } else {
        int r = bid - 512;   // og in [0,64), ch in [0,8)
        stats_body<256, 512>(bpA0, bpB0, bpC0, wpA0, wpB0, wpC0,
                             spart0, r >> 3, r & 7, 0);
    }
}

// ---------------------------------------------------------------------------
// K3: gemm1-fused(256) | stats1(512)                         -> 768 blocks
// ---------------------------------------------------------------------------
__global__ __launch_bounds__(256) void k3_sweep1(
    const unsigned short* __restrict__ bas9_1, const unsigned short* __restrict__ wc9_1,
    const float* __restrict__ bias1, float* __restrict__ x2,
    const uint2* __restrict__ bpA1, const uint2* __restrict__ bpB1,
    const unsigned short* __restrict__ bpC1,
    const uint2* __restrict__ wpA1, const uint2* __restrict__ wpB1,
    const unsigned short* __restrict__ wpC1,
    float* __restrict__ spart1)
{
    __shared__ float Tsh[4][16][17];
    int bid = blockIdx.x;
    if (bid < 256) {
        gemm1_fused(bas9_1, wc9_1, bias1, x2, bid, Tsh);
    } else {
        int r = bid - 256;   // og in [0,32), ch in [0,8), isp in {0,1}
        int og = r >> 4, rem = r & 15;
        stats_body<512, 256>(bpA1, bpB1, bpC1, wpA1, wpB1, wpC1,
                             spart1, og, rem & 7, rem >> 3);
    }
}

// ---------------------------------------------------------------------------
// K4: statsfin0(512) | statsfin1(512)                        -> 1024 blocks
// ---------------------------------------------------------------------------
__global__ __launch_bounds__(256) void k4_fin(
    const float* __restrict__ spart0, const float* __restrict__ grid0,
    float* __restrict__ sc0, float* __restrict__ st0,
    const float* __restrict__ spart1, const float* __restrict__ grid1,
    float* __restrict__ sc1, float* __restrict__ st1)
{
    int bid = blockIdx.x, t = threadIdx.x;
    if (bid < 512) {
        statsfin_body(spart0, grid0, sc0, st0, 131072, bid * 256 + t);
    } else {
        statsfin_body(spart1, grid1, sc1, st1, 131072, (bid - 512) * 256 + t);
    }
}

// ---------------------------------------------------------------------------
extern "C" void kernel_launch(void* const* d_in, const int* in_sizes, int n_in,
                              void* d_out, int out_size, void* d_ws, size_t ws_size,
                              hipStream_t stream)
{
    const float* x     = (const float*)d_in[0];
    const float* grid0 = (const float*)d_in[1];
    const float* coef0 = (const float*)d_in[2];
    const float* sb0   = (const float*)d_in[3];
    const float* ssp0  = (const float*)d_in[4];
    const float* bias0 = (const float*)d_in[5];
    const float* grid1 = (const float*)d_in[6];
    const float* coef1 = (const float*)d_in[7];
    const float* sb1   = (const float*)d_in[8];
    const float* ssp1  = (const float*)d_in[9];
    const float* bias1 = (const float*)d_in[10];

    float* out = (float*)d_out;
    float* x2  = out;                 // (256,256)
    float* sc0 = out + 65536;         // (512,256)
    float* st0 = out + 196608;        // (512,256)
    float* sc1 = out + 327680;        // (256,512)
    float* st1 = out + 458752;        // (256,512)

    // Workspace (~44 MB, all disjoint)
    char* w = (char*)d_ws;
    unsigned short* wc9_0  = (unsigned short*)w; w += (size_t)512 * 3072 * 2;
    unsigned short* wc9_1  = (unsigned short*)w; w += (size_t)256 * 6144 * 2;
    unsigned short* bas9_0 = (unsigned short*)w; w += (size_t)256 * 3072 * 2;
    unsigned short* bas9_1 = (unsigned short*)w; w += (size_t)256 * 6144 * 2;
    uint2* wpA0 = (uint2*)w; w += (size_t)131072 * 8;
    uint2* wpB0 = (uint2*)w; w += (size_t)131072 * 8;
    uint2* wpA1 = (uint2*)w; w += (size_t)131072 * 8;
    uint2* wpB1 = (uint2*)w; w += (size_t)131072 * 8;
    uint2* bpA0 = (uint2*)w; w += (size_t)65536 * 8;
    uint2* bpB0 = (uint2*)w; w += (size_t)65536 * 8;
    uint2* bpA1 = (uint2*)w; w += (size_t)131072 * 8;
    uint2* bpB1 = (uint2*)w; w += (size_t)131072 * 8;
    unsigned short* wpC0 = (unsigned short*)w; w += (size_t)131072 * 2;
    unsigned short* wpC1 = (unsigned short*)w; w += (size_t)131072 * 2;
    unsigned short* bpC0 = (unsigned short*)w; w += (size_t)65536 * 2;
    unsigned short* bpC1 = (unsigned short*)w; w += (size_t)131072 * 2;
    float* spart0 = (float*)w; w += (size_t)8 * 3 * 131072 * 4;
    float* spart1 = (float*)w; w += (size_t)8 * 3 * 131072 * 4;

    k1_prep<<<1280, 256, 0, stream>>>(
        coef0, ssp0, sb0, wc9_0, wpA0, wpB0, wpC0,
        coef1, ssp1, sb1, wc9_1, wpA1, wpB1, wpC1,
        x, grid0, bas9_0, bpA0, bpB0, bpC0);

    k2_sweep0<<<1024, 256, 0, stream>>>(
        wc9_0, bas9_0, bias0, grid1, bas9_1, bpA1, bpB1, bpC1,
        bpA0, bpB0, bpC0, wpA0, wpB0, wpC0, spart0);

    k3_sweep1<<<768, 256, 0, stream>>>(
        bas9_1, wc9_1, bias1, x2,
        bpA1, bpB1, bpC1, wpA1, wpB1, wpC1, spart1);

    k4_fin<<<1024, 256, 0, stream>>>(
        spart0, grid0, sc0, st0, spart1, grid1, sc1, st1);
}

// Round 17
// 63.402 us; speedup vs baseline: 9.4190x; 1.1333x over previous
//
#include <hip/hip_runtime.h>
#include <math.h>

constexpr int BATCH = 256;

typedef short short8 __attribute__((ext_vector_type(8)));
typedef float f32x4 __attribute__((ext_vector_type(4)));

// ---------------------------------------------------------------------------
// bf16 helpers (RNE)
// ---------------------------------------------------------------------------
__device__ __forceinline__ unsigned short f2bf(float f) {
    unsigned int u = __float_as_uint(f);
    u += 0x7FFFu + ((u >> 16) & 1u);
    return (unsigned short)(u >> 16);
}
__device__ __forceinline__ unsigned int pack2(float a, float b) {
    return (unsigned int)f2bf(a) | ((unsigned int)f2bf(b) << 16);
}

// ---------------------------------------------------------------------------
// basis_eval: 8 cubic B-spline values + silu. out[0..7]=basis, out[8]=silu.
// ---------------------------------------------------------------------------
__device__ __forceinline__ void basis_eval(
    float x, const float* __restrict__ grid, int ii, float out[9])
{
    float g[6];
#pragma unroll
    for (int k = 0; k < 6; ++k) g[k] = grid[(size_t)ii * 6 + k];
    float h = (g[5] - g[0]) * 0.2f;

    float t[12];
    t[0] = g[0] - 3.f * h; t[1] = g[0] - 2.f * h; t[2] = g[0] - h;
#pragma unroll
    for (int k = 0; k < 6; ++k) t[3 + k] = g[k];
    t[9] = g[5] + h; t[10] = g[5] + 2.f * h; t[11] = g[5] + 3.f * h;

    float Bv[11];
#pragma unroll
    for (int j = 0; j < 11; ++j)
        Bv[j] = (x >= t[j] && x < t[j + 1]) ? 1.0f : 0.0f;

#pragma unroll
    for (int d = 1; d <= 3; ++d) {
#pragma unroll
        for (int j = 0; j + d < 11; ++j) {
            float left  = __fdividef(x - t[j],         t[j + d] - t[j]);
            float right = __fdividef(t[j + d + 1] - x, t[j + d + 1] - t[j + 1]);
            Bv[j] = left * Bv[j] + right * Bv[j + 1];
        }
    }

#pragma unroll
    for (int k = 0; k < 8; ++k) out[k] = Bv[k];
    out[8] = __fdividef(x, 1.0f + __expf(-x));
}

// store 9 floats as 24B bf16 gemm-pack record (12 slots, last 3 zero)
__device__ __forceinline__ void store_rec12(unsigned short* rec, const float v[9])
{
    uint2* p = (uint2*)rec;
    p[0] = make_uint2(pack2(v[0], v[1]), pack2(v[2], v[3]));
    p[1] = make_uint2(pack2(v[4], v[5]), pack2(v[6], v[7]));
    p[2] = make_uint2(pack2(v[8], 0.f), 0u);
}

// store 9 floats as 64B bf16 stats record (K=32, slots 9..31 zero)
__device__ __forceinline__ void store_rec32(unsigned short* rec, const float v[9])
{
    uint4* p = (uint4*)rec;
    p[0] = make_uint4(pack2(v[0], v[1]), pack2(v[2], v[3]),
                      pack2(v[4], v[5]), pack2(v[6], v[7]));
    p[1] = make_uint4(pack2(v[8], 0.f), 0u, 0u, 0u);
    p[2] = make_uint4(0u, 0u, 0u, 0u);
    p[3] = make_uint4(0u, 0u, 0u, 0u);
}

// ---------------------------------------------------------------------------
// merge: record s (= o*I+ii): [ssp*coef0..7, sb] -> 12-pack (gemm) + 32-rec
// ---------------------------------------------------------------------------
__device__ __forceinline__ void merge_body(
    const float* __restrict__ coef, const float* __restrict__ ssp,
    const float* __restrict__ sb, unsigned short* __restrict__ wc9,
    unsigned short* __restrict__ wc32, int s)
{
    float sspv = ssp[s], sbv = sb[s];
    const float4* c = (const float4*)(coef + (size_t)s * 8);
    float4 c0 = c[0], c1 = c[1];
    float v[9] = { sspv * c0.x, sspv * c0.y, sspv * c0.z, sspv * c0.w,
                   sspv * c1.x, sspv * c1.y, sspv * c1.z, sspv * c1.w, sbv };
    store_rec12(wc9 + (size_t)s * 12, v);
    store_rec32(wc32 + (size_t)s * 32, v);
}

// ---------------------------------------------------------------------------
// gemm0 fused (512 tasks = 32 mt x 16 nt): one 16x16 tile (m=ii, n=b),
// 4 waves split K (K2=3072 -> 24-MFMA chain each), LDS reduce.
// Epilogue: xmid = D + bias0 -> basis_eval -> bas9_1 pack + bas32_1 record.
// ---------------------------------------------------------------------------
__device__ __forceinline__ void gemm0_fused(
    const unsigned short* __restrict__ wc9_0, const unsigned short* __restrict__ bas9_0,
    const float* __restrict__ bias0, const float* __restrict__ grid1,
    unsigned short* __restrict__ bas9_1, unsigned short* __restrict__ bas32_1,
    int bid, float (*T)[16][17])
{
    constexpr int K2 = 3072, KW = K2 / 4;
    int mt = bid >> 4, nt = bid & 15;
    int t = threadIdx.x, l = t & 63, w = t >> 6;
    int m0 = mt * 16;            // ii base (layer-1 input)
    int n0 = nt * 16;            // b base

    const unsigned short* pa = wc9_0  + (size_t)(m0 + (l & 15)) * K2 + w * KW + ((l >> 4) * 8);
    const unsigned short* pb = bas9_0 + (size_t)(n0 + (l & 15)) * K2 + w * KW + ((l >> 4) * 8);

    f32x4 acc = {0.f, 0.f, 0.f, 0.f};
#pragma unroll 8
    for (int kk = 0; kk < KW / 32; ++kk) {   // 24 steps
        short8 av = *(const short8*)pa; pa += 32;
        short8 bv = *(const short8*)pb; pb += 32;
        acc = __builtin_amdgcn_mfma_f32_16x16x32_bf16(av, bv, acc, 0, 0, 0);
    }

#pragma unroll
    for (int r = 0; r < 4; ++r)
        T[w][(l >> 4) * 4 + r][l & 15] = acc[r];   // [m_loc][n_loc]
    __syncthreads();

    int ii_loc = t & 15, b_loc = t >> 4;     // thread owns one element
    float d = T[0][ii_loc][b_loc] + T[1][ii_loc][b_loc]
            + T[2][ii_loc][b_loc] + T[3][ii_loc][b_loc];
    int ii = m0 + ii_loc;
    float xv = d + bias0[ii];
    float out[9];
    basis_eval(xv, grid1, ii, out);
    size_t p = (size_t)(n0 + b_loc) * 512 + ii;
    store_rec12(bas9_1 + p * 12, out);
    store_rec32(bas32_1 + p * 32, out);
    __syncthreads();
}

// ---------------------------------------------------------------------------
// gemm1 fused (256 tasks = 16 mt x 16 nt): one 16x16 tile (m=b, n=o),
// 4 waves split K (K2=6144 -> 48-MFMA chain each), LDS reduce.
// Epilogue: x2[b][o] = D + bias1[o].
// ---------------------------------------------------------------------------
__device__ __forceinline__ void gemm1_fused(
    const unsigned short* __restrict__ bas9_1, const unsigned short* __restrict__ wc9_1,
    const float* __restrict__ bias1, float* __restrict__ x2, int bid, float (*T)[16][17])
{
    constexpr int K2 = 6144, KW = K2 / 4;
    int mt = bid >> 4, nt = bid & 15;
    int t = threadIdx.x, l = t & 63, w = t >> 6;
    int m0 = mt * 16;            // b base
    int n0 = nt * 16;            // o base

    const unsigned short* pa = bas9_1 + (size_t)(m0 + (l & 15)) * K2 + w * KW + ((l >> 4) * 8);
    const unsigned short* pb = wc9_1  + (size_t)(n0 + (l & 15)) * K2 + w * KW + ((l >> 4) * 8);

    f32x4 acc = {0.f, 0.f, 0.f, 0.f};
#pragma unroll 8
    for (int kk = 0; kk < KW / 32; ++kk) {   // 48 steps
        short8 av = *(const short8*)pa; pa += 32;
        short8 bv = *(const short8*)pb; pb += 32;
        acc = __builtin_amdgcn_mfma_f32_16x16x32_bf16(av, bv, acc, 0, 0, 0);
    }

#pragma unroll
    for (int r = 0; r < 4; ++r)
        T[w][(l >> 4) * 4 + r][l & 15] = acc[r];   // [b_loc][o_loc]
    __syncthreads();

    int o_loc = t & 15, b_loc = t >> 4;
    float d = T[0][b_loc][o_loc] + T[1][b_loc][o_loc]
            + T[2][b_loc][o_loc] + T[3][b_loc][o_loc];
    int o = n0 + o_loc;
    x2[(size_t)(m0 + b_loc) * 256 + o] = d + bias1[o];
}

// ---------------------------------------------------------------------------
// stats via MFMA: one wave-task = (og, ii) covering 64 o's x all 256 b.
// A = bas32 (row=b), B = wc32 (row=o), D[row=b][col=o] = y (K=32, 9 valid).
// Per b-tile: 1 A-load + 4 zero-C MFMA + 12 VALU per q. Final: shfl_xor
// tree over lane>>4 groups -> full sums over 256 b -> finalize sc/st inline.
// Deterministic (fixed order, no atomics). Template I in {256,512}.
// ---------------------------------------------------------------------------
template <int I>
__device__ __forceinline__ void stats_mfma(
    const unsigned short* __restrict__ bas32, const unsigned short* __restrict__ wc32,
    const float* __restrict__ grid, float* __restrict__ sc, float* __restrict__ st,
    int id)   // id = og * I + ii
{
    int og = id / I, ii = id % I;
    int l = threadIdx.x & 63;
    int row = l & 15, chunk = l >> 4;

    short8 bfrag[4];
#pragma unroll
    for (int q = 0; q < 4; ++q) {
        int o = og * 64 + q * 16 + row;
        bfrag[q] = *(const short8*)(wc32 + ((size_t)o * I + ii) * 32 + chunk * 8);
    }

    float ab[4], sm[4], sq[4];
#pragma unroll
    for (int q = 0; q < 4; ++q) { ab[q] = 0.f; sm[q] = 0.f; sq[q] = 0.f; }

    for (int bt = 0; bt < 16; ++bt) {
        int b = bt * 16 + row;
        short8 av = *(const short8*)(bas32 + ((size_t)b * I + ii) * 32 + chunk * 8);
#pragma unroll
        for (int q = 0; q < 4; ++q) {
            f32x4 d = {0.f, 0.f, 0.f, 0.f};
            d = __builtin_amdgcn_mfma_f32_16x16x32_bf16(av, bfrag[q], d, 0, 0, 0);
#pragma unroll
            for (int r = 0; r < 4; ++r) {
                float y = d[r];
                ab[q] += fabsf(y);
                sm[q] += y;
                sq[q] = fmaf(y, y, sq[q]);
            }
        }
    }

    // combine the 4 lane-groups (each covered b rows (chunk*4..chunk*4+3)+16*bt)
#pragma unroll
    for (int q = 0; q < 4; ++q) {
        ab[q] += __shfl_xor(ab[q], 16); ab[q] += __shfl_xor(ab[q], 32);
        sm[q] += __shfl_xor(sm[q], 16); sm[q] += __shfl_xor(sm[q], 32);
        sq[q] += __shfl_xor(sq[q], 16); sq[q] += __shfl_xor(sq[q], 32);
    }

    if (l < 16) {
#pragma unroll
        for (int q = 0; q < 4; ++q) {
            int o = og * 64 + q * 16 + l;
            size_t s = (size_t)o * I + ii;
            float range = grid[s * 6 + 5] - grid[s * 6] + 1e-4f;
            sc[s] = (ab[q] * (1.0f / BATCH)) / range;
            float var = (sq[q] - sm[q] * sm[q] * (1.0f / BATCH)) * (1.0f / (BATCH - 1));
            st[s] = sqrtf(fmaxf(var, 0.0f));
        }
    }
}

// ---------------------------------------------------------------------------
// K1: merge0(512) | merge1(512) | basis0(256, ii-lane-fast)  -> 1280 blocks
// ---------------------------------------------------------------------------
__global__ __launch_bounds__(256) void k1_prep(
    const float* __restrict__ coef0, const float* __restrict__ ssp0,
    const float* __restrict__ sb0,   unsigned short* __restrict__ wc9_0,
    unsigned short* __restrict__ wc32_0,
    const float* __restrict__ coef1, const float* __restrict__ ssp1,
    const float* __restrict__ sb1,   unsigned short* __restrict__ wc9_1,
    unsigned short* __restrict__ wc32_1,
    const float* __restrict__ x, const float* __restrict__ grid0,
    unsigned short* __restrict__ bas9_0, unsigned short* __restrict__ bas32_0)
{
    int bid = blockIdx.x, t = threadIdx.x;
    if (bid < 512)  { merge_body(coef0, ssp0, sb0, wc9_0, wc32_0, bid * 256 + t); return; }
    if (bid < 1024) { merge_body(coef1, ssp1, sb1, wc9_1, wc32_1, (bid - 512) * 256 + t); return; }
    int tile = bid - 1024;                 // 16 bt x 16 it
    int bt = tile >> 4, it = tile & 15;
    int ii = it * 16 + (t & 15), b = bt * 16 + (t >> 4);
    float out[9];
    basis_eval(x[(size_t)b * 256 + ii], grid0, ii, out);
    size_t p = (size_t)b * 256 + ii;
    store_rec12(bas9_0 + p * 12, out);
    store_rec32(bas32_0 + p * 32, out);
}

// ---------------------------------------------------------------------------
// K2: gemm0-fused(512) | stats0-mfma(512 -> 2048 wave-tasks) -> 1024 blocks
// ---------------------------------------------------------------------------
__global__ __launch_bounds__(256) void k2_sweep0(
    const unsigned short* __restrict__ wc9_0, const unsigned short* __restrict__ bas9_0,
    const float* __restrict__ bias0, const float* __restrict__ grid1,
    unsigned short* __restrict__ bas9_1, unsigned short* __restrict__ bas32_1,
    const unsigned short* __restrict__ bas32_0, const unsigned short* __restrict__ wc32_0,
    const float* __restrict__ grid0, float* __restrict__ sc0, float* __restrict__ st0)
{
    __shared__ float Tsh[4][16][17];
    int bid = blockIdx.x;
    if (bid < 512) {
        gemm0_fused(wc9_0, bas9_0, bias0, grid1, bas9_1, bas32_1, bid, Tsh);
    } else {
        int id = (bid - 512) * 4 + (threadIdx.x >> 6);   // 2048 tasks: og in [0,8), ii in [0,256)
        stats_mfma<256>(bas32_0, wc32_0, grid0, sc0, st0, id);
    }
}

// ---------------------------------------------------------------------------
// K3: gemm1-fused(256) | stats1-mfma(512 -> 2048 wave-tasks) -> 768 blocks
// ---------------------------------------------------------------------------
__global__ __launch_bounds__(256) void k3_sweep1(
    const unsigned short* __restrict__ bas9_1, const unsigned short* __restrict__ wc9_1,
    const float* __restrict__ bias1, float* __restrict__ x2,
    const unsigned short* __restrict__ bas32_1, const unsigned short* __restrict__ wc32_1,
    const float* __restrict__ grid1, float* __restrict__ sc1, float* __restrict__ st1)
{
    __shared__ float Tsh[4][16][17];
    int bid = blockIdx.x;
    if (bid < 256) {
        gemm1_fused(bas9_1, wc9_1, bias1, x2, bid, Tsh);
    } else {
        int id = (bid - 256) * 4 + (threadIdx.x >> 6);   // 2048 tasks: og in [0,4), ii in [0,512)
        stats_mfma<512>(bas32_1, wc32_1, grid1, sc1, st1, id);
    }
}

// ---------------------------------------------------------------------------
extern "C" void kernel_launch(void* const* d_in, const int* in_sizes, int n_in,
                              void* d_out, int out_size, void* d_ws, size_t ws_size,
                              hipStream_t stream)
{
    const float* x     = (const float*)d_in[0];
    const float* grid0 = (const float*)d_in[1];
    const float* coef0 = (const float*)d_in[2];
    const float* sb0   = (const float*)d_in[3];
    const float* ssp0  = (const float*)d_in[4];
    const float* bias0 = (const float*)d_in[5];
    const float* grid1 = (const float*)d_in[6];
    const float* coef1 = (const float*)d_in[7];
    const float* sb1   = (const float*)d_in[8];
    const float* ssp1  = (const float*)d_in[9];
    const float* bias1 = (const float*)d_in[10];

    float* out = (float*)d_out;
    float* x2  = out;                 // (256,256)
    float* sc0 = out + 65536;         // (512,256)
    float* st0 = out + 196608;        // (512,256)
    float* sc1 = out + 327680;        // (256,512)
    float* st1 = out + 458752;        // (256,512)

    // Workspace (~40 MB, all disjoint)
    char* w = (char*)d_ws;
    unsigned short* wc9_0   = (unsigned short*)w; w += (size_t)512 * 3072 * 2;
    unsigned short* wc9_1   = (unsigned short*)w; w += (size_t)256 * 6144 * 2;
    unsigned short* bas9_0  = (unsigned short*)w; w += (size_t)256 * 3072 * 2;
    unsigned short* bas9_1  = (unsigned short*)w; w += (size_t)256 * 6144 * 2;
    unsigned short* wc32_0  = (unsigned short*)w; w += (size_t)131072 * 32 * 2;
    unsigned short* wc32_1  = (unsigned short*)w; w += (size_t)131072 * 32 * 2;
    unsigned short* bas32_0 = (unsigned short*)w; w += (size_t)65536 * 32 * 2;
    unsigned short* bas32_1 = (unsigned short*)w; w += (size_t)131072 * 32 * 2;

    k1_prep<<<1280, 256, 0, stream>>>(
        coef0, ssp0, sb0, wc9_0, wc32_0,
        coef1, ssp1, sb1, wc9_1, wc32_1,
        x, grid0, bas9_0, bas32_0);

    k2_sweep0<<<1024, 256, 0, stream>>>(
        wc9_0, bas9_0, bias0, grid1, bas9_1, bas32_1,
        bas32_0, wc32_0, grid0, sc0, st0);

    k3_sweep1<<<768, 256, 0, stream>>>(
        bas9_1, wc9_1, bias1, x2,
        bas32_1, wc32_1, grid1, sc1, st1);
}

// Round 18
// 57.099 us; speedup vs baseline: 10.4589x; 1.1104x over previous
//
#include <hip/hip_runtime.h>
#include <math.h>

constexpr int BATCH = 256;

typedef short short8 __attribute__((ext_vector_type(8)));
typedef float f32x4 __attribute__((ext_vector_type(4)));
typedef float f32x16 __attribute__((ext_vector_type(16)));

// ---------------------------------------------------------------------------
// bf16 helpers (RNE)
// ---------------------------------------------------------------------------
__device__ __forceinline__ unsigned short f2bf(float f) {
    unsigned int u = __float_as_uint(f);
    u += 0x7FFFu + ((u >> 16) & 1u);
    return (unsigned short)(u >> 16);
}
__device__ __forceinline__ unsigned int pack2(float a, float b) {
    return (unsigned int)f2bf(a) | ((unsigned int)f2bf(b) << 16);
}

// ---------------------------------------------------------------------------
// basis_eval: 8 cubic B-spline values + silu. out[0..7]=basis, out[8]=silu.
// ---------------------------------------------------------------------------
__device__ __forceinline__ void basis_eval(
    float x, const float* __restrict__ grid, int ii, float out[9])
{
    float g[6];
#pragma unroll
    for (int k = 0; k < 6; ++k) g[k] = grid[(size_t)ii * 6 + k];
    float h = (g[5] - g[0]) * 0.2f;

    float t[12];
    t[0] = g[0] - 3.f * h; t[1] = g[0] - 2.f * h; t[2] = g[0] - h;
#pragma unroll
    for (int k = 0; k < 6; ++k) t[3 + k] = g[k];
    t[9] = g[5] + h; t[10] = g[5] + 2.f * h; t[11] = g[5] + 3.f * h;

    float Bv[11];
#pragma unroll
    for (int j = 0; j < 11; ++j)
        Bv[j] = (x >= t[j] && x < t[j + 1]) ? 1.0f : 0.0f;

#pragma unroll
    for (int d = 1; d <= 3; ++d) {
#pragma unroll
        for (int j = 0; j + d < 11; ++j) {
            float left  = __fdividef(x - t[j],         t[j + d] - t[j]);
            float right = __fdividef(t[j + d + 1] - x, t[j + d + 1] - t[j + 1]);
            Bv[j] = left * Bv[j] + right * Bv[j + 1];
        }
    }

#pragma unroll
    for (int k = 0; k < 8; ++k) out[k] = Bv[k];
    out[8] = __fdividef(x, 1.0f + __expf(-x));
}

// store 9 floats as one 32B bf16 record (16 slots, 9..15 zero)
__device__ __forceinline__ void store_rec16(unsigned short* rec, const float v[9])
{
    uint4* p = (uint4*)rec;
    p[0] = make_uint4(pack2(v[0], v[1]), pack2(v[2], v[3]),
                      pack2(v[4], v[5]), pack2(v[6], v[7]));
    p[1] = make_uint4(pack2(v[8], 0.f), 0u, 0u, 0u);
}

// ---------------------------------------------------------------------------
// merge: record s (= o*I+ii): [ssp*coef0..7, sb, 0..0] -> 32B record
// ---------------------------------------------------------------------------
__device__ __forceinline__ void merge_body(
    const float* __restrict__ coef, const float* __restrict__ ssp,
    const float* __restrict__ sb, unsigned short* __restrict__ wc16, int s)
{
    float sspv = ssp[s], sbv = sb[s];
    const float4* c = (const float4*)(coef + (size_t)s * 8);
    float4 c0 = c[0], c1 = c[1];
    float v[9] = { sspv * c0.x, sspv * c0.y, sspv * c0.z, sspv * c0.w,
                   sspv * c1.x, sspv * c1.y, sspv * c1.z, sspv * c1.w, sbv };
    store_rec16(wc16 + (size_t)s * 16, v);
}

// ---------------------------------------------------------------------------
// gemm0 fused (512 tasks = 32 mt x 16 nt): one 16x16 tile (m=ii, n=b),
// 4 waves split K (K2=4096 -> 32-MFMA chain each), LDS reduce.
// Epilogue: xmid = D + bias0 -> basis_eval -> bas16_1 record.
// ---------------------------------------------------------------------------
__device__ __forceinline__ void gemm0_fused(
    const unsigned short* __restrict__ wc16_0, const unsigned short* __restrict__ bas16_0,
    const float* __restrict__ bias0, const float* __restrict__ grid1,
    unsigned short* __restrict__ bas16_1, int bid, float (*T)[16][17])
{
    constexpr int K2 = 256 * 16, KW = K2 / 4;
    int mt = bid >> 4, nt = bid & 15;
    int t = threadIdx.x, l = t & 63, w = t >> 6;
    int m0 = mt * 16;            // ii base (layer-1 input)
    int n0 = nt * 16;            // b base

    const unsigned short* pa = wc16_0  + (size_t)(m0 + (l & 15)) * K2 + w * KW + ((l >> 4) * 8);
    const unsigned short* pb = bas16_0 + (size_t)(n0 + (l & 15)) * K2 + w * KW + ((l >> 4) * 8);

    f32x4 acc = {0.f, 0.f, 0.f, 0.f};
#pragma unroll 8
    for (int kk = 0; kk < KW / 32; ++kk) {   // 32 steps
        short8 av = *(const short8*)pa; pa += 32;
        short8 bv = *(const short8*)pb; pb += 32;
        acc = __builtin_amdgcn_mfma_f32_16x16x32_bf16(av, bv, acc, 0, 0, 0);
    }

#pragma unroll
    for (int r = 0; r < 4; ++r)
        T[w][(l >> 4) * 4 + r][l & 15] = acc[r];   // [m_loc][n_loc]
    __syncthreads();

    int ii_loc = t & 15, b_loc = t >> 4;     // thread owns one element
    float d = T[0][ii_loc][b_loc] + T[1][ii_loc][b_loc]
            + T[2][ii_loc][b_loc] + T[3][ii_loc][b_loc];
    int ii = m0 + ii_loc;
    float xv = d + bias0[ii];
    float out[9];
    basis_eval(xv, grid1, ii, out);
    store_rec16(bas16_1 + ((size_t)(n0 + b_loc) * 512 + ii) * 16, out);
    __syncthreads();
}

// ---------------------------------------------------------------------------
// gemm1 fused (256 tasks = 16 mt x 16 nt): one 16x16 tile (m=b, n=o),
// 4 waves split K (K2=8192 -> 64-MFMA chain each), LDS reduce.
// Epilogue: x2[b][o] = D + bias1[o].
// ---------------------------------------------------------------------------
__device__ __forceinline__ void gemm1_fused(
    const unsigned short* __restrict__ bas16_1, const unsigned short* __restrict__ wc16_1,
    const float* __restrict__ bias1, float* __restrict__ x2, int bid, float (*T)[16][17])
{
    constexpr int K2 = 512 * 16, KW = K2 / 4;
    int mt = bid >> 4, nt = bid & 15;
    int t = threadIdx.x, l = t & 63, w = t >> 6;
    int m0 = mt * 16;            // b base
    int n0 = nt * 16;            // o base

    const unsigned short* pa = bas16_1 + (size_t)(m0 + (l & 15)) * K2 + w * KW + ((l >> 4) * 8);
    const unsigned short* pb = wc16_1  + (size_t)(n0 + (l & 15)) * K2 + w * KW + ((l >> 4) * 8);

    f32x4 acc = {0.f, 0.f, 0.f, 0.f};
#pragma unroll 8
    for (int kk = 0; kk < KW / 32; ++kk) {   // 64 steps
        short8 av = *(const short8*)pa; pa += 32;
        short8 bv = *(const short8*)pb; pb += 32;
        acc = __builtin_amdgcn_mfma_f32_16x16x32_bf16(av, bv, acc, 0, 0, 0);
    }

#pragma unroll
    for (int r = 0; r < 4; ++r)
        T[w][(l >> 4) * 4 + r][l & 15] = acc[r];   // [b_loc][o_loc]
    __syncthreads();

    int o_loc = t & 15, b_loc = t >> 4;
    float d = T[0][b_loc][o_loc] + T[1][b_loc][o_loc]
            + T[2][b_loc][o_loc] + T[3][b_loc][o_loc];
    int o = n0 + o_loc;
    x2[(size_t)(m0 + b_loc) * 256 + o] = d + bias1[o];
}

// ---------------------------------------------------------------------------
// stats via 32x32x16 MFMA: one wave-task = (og, ii) covering 32 o's x 256 b.
// A = bas16 (row=b), B = wc16 (row=o), D[row=b][col=o] = y (K=16, 9 valid).
// Per b-tile (32 b's): 1 A-load + 1 MFMA + 48 VALU. D col=lane&31 (verified);
// row mapping irrelevant (we sum over all rows). shfl_xor(32) -> full b-sum.
// Deterministic, no atomics. Template I in {256,512}.
// ---------------------------------------------------------------------------
template <int I>
__device__ __forceinline__ void stats_mfma(
    const unsigned short* __restrict__ bas16, const unsigned short* __restrict__ wc16,
    const float* __restrict__ grid, float* __restrict__ sc, float* __restrict__ st,
    int id)   // id = og * I + ii
{
    int og = id / I, ii = id % I;
    int l = threadIdx.x & 63;
    int row = l & 31, chunk = l >> 5;

    short8 bfrag = *(const short8*)(
        wc16 + ((size_t)(og * 32 + row) * I + ii) * 16 + chunk * 8);

    float ab = 0.f, sm = 0.f, sq = 0.f;
    for (int bt = 0; bt < BATCH / 32; ++bt) {   // 8 tiles
        int b = bt * 32 + row;
        short8 av = *(const short8*)(
            bas16 + ((size_t)b * I + ii) * 16 + chunk * 8);
        f32x16 d;
#pragma unroll
        for (int r = 0; r < 16; ++r) d[r] = 0.f;
        d = __builtin_amdgcn_mfma_f32_32x32x16_bf16(av, bfrag, d, 0, 0, 0);
#pragma unroll
        for (int r = 0; r < 16; ++r) {
            float y = d[r];
            ab += fabsf(y);
            sm += y;
            sq = fmaf(y, y, sq);
        }
    }

    ab += __shfl_xor(ab, 32);
    sm += __shfl_xor(sm, 32);
    sq += __shfl_xor(sq, 32);

    if (l < 32) {
        int o = og * 32 + l;
        size_t s = (size_t)o * I + ii;
        float range = grid[s * 6 + 5] - grid[s * 6] + 1e-4f;
        sc[s] = (ab * (1.0f / BATCH)) / range;
        float var = (sq - sm * sm * (1.0f / BATCH)) * (1.0f / (BATCH - 1));
        st[s] = sqrtf(fmaxf(var, 0.0f));
    }
}

// ---------------------------------------------------------------------------
// K1: merge0(512) | merge1(512) | basis0(256, ii-lane-fast)  -> 1280 blocks
// ---------------------------------------------------------------------------
__global__ __launch_bounds__(256) void k1_prep(
    const float* __restrict__ coef0, const float* __restrict__ ssp0,
    const float* __restrict__ sb0,   unsigned short* __restrict__ wc16_0,
    const float* __restrict__ coef1, const float* __restrict__ ssp1,
    const float* __restrict__ sb1,   unsigned short* __restrict__ wc16_1,
    const float* __restrict__ x, const float* __restrict__ grid0,
    unsigned short* __restrict__ bas16_0)
{
    int bid = blockIdx.x, t = threadIdx.x;
    if (bid < 512)  { merge_body(coef0, ssp0, sb0, wc16_0, bid * 256 + t); return; }
    if (bid < 1024) { merge_body(coef1, ssp1, sb1, wc16_1, (bid - 512) * 256 + t); return; }
    int tile = bid - 1024;                 // 16 bt x 16 it
    int bt = tile >> 4, it = tile & 15;
    int ii = it * 16 + (t & 15), b = bt * 16 + (t >> 4);
    float out[9];
    basis_eval(x[(size_t)b * 256 + ii], grid0, ii, out);
    store_rec16(bas16_0 + ((size_t)b * 256 + ii) * 16, out);
}

// ---------------------------------------------------------------------------
// K2: gemm0-fused(512) | stats0-mfma(1024 -> 4096 wave-tasks) -> 1536 blocks
// ---------------------------------------------------------------------------
__global__ __launch_bounds__(256) void k2_sweep0(
    const unsigned short* __restrict__ wc16_0, const unsigned short* __restrict__ bas16_0,
    const float* __restrict__ bias0, const float* __restrict__ grid1,
    unsigned short* __restrict__ bas16_1,
    const float* __restrict__ grid0, float* __restrict__ sc0, float* __restrict__ st0)
{
    __shared__ float Tsh[4][16][17];
    int bid = blockIdx.x;
    if (bid < 512) {
        gemm0_fused(wc16_0, bas16_0, bias0, grid1, bas16_1, bid, Tsh);
    } else {
        // 4096 tasks: og in [0,16), ii in [0,256)
        int id = (bid - 512) * 4 + (threadIdx.x >> 6);
        stats_mfma<256>(bas16_0, wc16_0, grid0, sc0, st0, id);
    }
}

// ---------------------------------------------------------------------------
// K3: gemm1-fused(256) | stats1-mfma(1024 -> 4096 wave-tasks) -> 1280 blocks
// ---------------------------------------------------------------------------
__global__ __launch_bounds__(256) void k3_sweep1(
    const unsigned short* __restrict__ bas16_1, const unsigned short* __restrict__ wc16_1,
    const float* __restrict__ bias1, float* __restrict__ x2,
    const float* __restrict__ grid1, float* __restrict__ sc1, float* __restrict__ st1)
{
    __shared__ float Tsh[4][16][17];
    int bid = blockIdx.x;
    if (bid < 256) {
        gemm1_fused(bas16_1, wc16_1, bias1, x2, bid, Tsh);
    } else {
        // 4096 tasks: og in [0,8), ii in [0,512)
        int id = (bid - 256) * 4 + (threadIdx.x >> 6);
        stats_mfma<512>(bas16_1, wc16_1, grid1, sc1, st1, id);
    }
}

// ---------------------------------------------------------------------------
extern "C" void kernel_launch(void* const* d_in, const int* in_sizes, int n_in,
                              void* d_out, int out_size, void* d_ws, size_t ws_size,
                              hipStream_t stream)
{
    const float* x     = (const float*)d_in[0];
    const float* grid0 = (const float*)d_in[1];
    const float* coef0 = (const float*)d_in[2];
    const float* sb0   = (const float*)d_in[3];
    const float* ssp0  = (const float*)d_in[4];
    const float* bias0 = (const float*)d_in[5];
    const float* grid1 = (const float*)d_in[6];
    const float* coef1 = (const float*)d_in[7];
    const float* sb1   = (const float*)d_in[8];
    const float* ssp1  = (const float*)d_in[9];
    const float* bias1 = (const float*)d_in[10];

    float* out = (float*)d_out;
    float* x2  = out;                 // (256,256)
    float* sc0 = out + 65536;         // (512,256)
    float* st0 = out + 196608;        // (512,256)
    float* sc1 = out + 327680;        // (256,512)
    float* st1 = out + 458752;        // (256,512)

    // Workspace (~14 MB, all disjoint): one 32B record per element.
    char* w = (char*)d_ws;
    unsigned short* wc16_0  = (unsigned short*)w; w += (size_t)131072 * 32;
    unsigned short* wc16_1  = (unsigned short*)w; w += (size_t)131072 * 32;
    unsigned short* bas16_0 = (unsigned short*)w; w += (size_t)65536 * 32;
    unsigned short* bas16_1 = (unsigned short*)w; w += (size_t)131072 * 32;

    k1_prep<<<1280, 256, 0, stream>>>(
        coef0, ssp0, sb0, wc16_0,
        coef1, ssp1, sb1, wc16_1,
        x, grid0, bas16_0);

    k2_sweep0<<<1536, 256, 0, stream>>>(
        wc16_0, bas16_0, bias0, grid1, bas16_1, grid0, sc0, st0);

    k3_sweep1<<<1280, 256, 0, stream>>>(
        bas16_1, wc16_1, bias1, x2, grid1, sc1, st1);
}